// Round 1
// baseline (432.207 us; speedup 1.0000x reference)
//
#include <hip/hip_runtime.h>
#include <cstdint>

// BlockwiseWTA: per 512-elem block keep top-32 values, zero the rest.
// One wave (64 lanes) per block; 8 elems/lane via two float4 loads.
// Threshold found by greedy MSB-first bitwise search on order-preserving
// uint keys, with ballot-bitplane wave counts and early exit at count==32.
// Exact jax.lax.top_k tie semantics (lower index wins) via rare slow path.

__global__ __launch_bounds__(256) void wta_kernel(const float* __restrict__ x,
                                                  float* __restrict__ out) {
    const uint32_t wave = blockIdx.x * 4u + (threadIdx.x >> 6);
    const uint32_t lane = threadIdx.x & 63u;
    const size_t base = (size_t)wave * 512u;

    const float4* in4 = reinterpret_cast<const float4*>(x + base);
    float4 a = in4[lane];        // elements [4*lane, 4*lane+4)
    float4 b = in4[lane + 64u];  // elements [256+4*lane, ...)

    float v[8] = {a.x, a.y, a.z, a.w, b.x, b.y, b.z, b.w};
    uint32_t k[8];
#pragma unroll
    for (int i = 0; i < 8; ++i) {
        uint32_t u = __float_as_uint(v[i]);
        // order-preserving map: negatives -> ~u, positives -> u | signbit
        k[i] = (u & 0x80000000u) ? ~u : (u | 0x80000000u);
    }

    // Greedy: largest T such that count(keys >= T) >= 32.
    uint32_t T = 0u;
    bool exact = false;
#pragma unroll 1
    for (int bpos = 31; bpos >= 0; --bpos) {
        uint32_t cand = T | (1u << bpos);
        uint32_t cnt = 0;
#pragma unroll
        for (int i = 0; i < 8; ++i) cnt += (k[i] >= cand) ? 1u : 0u;
        // wave-wide sum of 4-bit counts via ballot bit-planes
        uint32_t total = (uint32_t)__popcll(__ballot((cnt & 1u) != 0u))
                       + ((uint32_t)__popcll(__ballot((cnt & 2u) != 0u)) << 1)
                       + ((uint32_t)__popcll(__ballot((cnt & 4u) != 0u)) << 2)
                       + ((uint32_t)__popcll(__ballot((cnt & 8u) != 0u)) << 3);
        if (total >= 32u) {
            T = cand;
            if (total == 32u) { exact = true; break; }
        }
    }

    bool keep[8];
#pragma unroll
    for (int i = 0; i < 8; ++i) keep[i] = (k[i] >= T);

    if (!exact) {
        // count(>=T) may exceed 32 (ties at the boundary value).
        uint32_t above = 0, eq = 0;
#pragma unroll
        for (int i = 0; i < 8; ++i) {
            above += (k[i] > T) ? 1u : 0u;
            eq    += (k[i] == T) ? 1u : 0u;
        }
        uint32_t nAbove = (uint32_t)__popcll(__ballot((above & 1u) != 0u))
                        + ((uint32_t)__popcll(__ballot((above & 2u) != 0u)) << 1)
                        + ((uint32_t)__popcll(__ballot((above & 4u) != 0u)) << 2)
                        + ((uint32_t)__popcll(__ballot((above & 8u) != 0u)) << 3);
        uint32_t nEq    = (uint32_t)__popcll(__ballot((eq & 1u) != 0u))
                        + ((uint32_t)__popcll(__ballot((eq & 2u) != 0u)) << 1)
                        + ((uint32_t)__popcll(__ballot((eq & 4u) != 0u)) << 2)
                        + ((uint32_t)__popcll(__ballot((eq & 8u) != 0u)) << 3);
        if (nAbove + nEq > 32u) {
            // Tie-break: keep first (32 - nAbove) equal-to-T elems by index.
            uint32_t r = 32u - nAbove;
            uint64_t m[8];
#pragma unroll
            for (int i = 0; i < 8; ++i) m[i] = __ballot(k[i] == T);
            uint64_t below = (lane == 0) ? 0ull : (~0ull >> (64u - lane));
            // first half: element position 4*lane + i, i in 0..3
            uint32_t c0 = (uint32_t)(__popcll(m[0] & below) + __popcll(m[1] & below)
                                   + __popcll(m[2] & below) + __popcll(m[3] & below));
            uint32_t e0 = (k[0] == T), e1 = (k[1] == T), e2 = (k[2] == T);
            uint32_t p0 = c0;
            uint32_t p1 = c0 + e0;
            uint32_t p2 = p1 + e1;
            uint32_t p3 = p2 + e2;
            uint32_t firstHalfEq = (uint32_t)(__popcll(m[0]) + __popcll(m[1])
                                            + __popcll(m[2]) + __popcll(m[3]));
            uint32_t c1 = (uint32_t)(__popcll(m[4] & below) + __popcll(m[5] & below)
                                   + __popcll(m[6] & below) + __popcll(m[7] & below));
            uint32_t e4 = (k[4] == T), e5 = (k[5] == T), e6 = (k[6] == T);
            uint32_t p4 = firstHalfEq + c1;
            uint32_t p5 = p4 + e4;
            uint32_t p6 = p5 + e5;
            uint32_t p7 = p6 + e6;
            keep[0] = (k[0] > T) || ((k[0] == T) && (p0 < r));
            keep[1] = (k[1] > T) || ((k[1] == T) && (p1 < r));
            keep[2] = (k[2] > T) || ((k[2] == T) && (p2 < r));
            keep[3] = (k[3] > T) || ((k[3] == T) && (p3 < r));
            keep[4] = (k[4] > T) || ((k[4] == T) && (p4 < r));
            keep[5] = (k[5] > T) || ((k[5] == T) && (p5 < r));
            keep[6] = (k[6] > T) || ((k[6] == T) && (p6 < r));
            keep[7] = (k[7] > T) || ((k[7] == T) && (p7 < r));
        }
    }

    float4 oa, ob;
    oa.x = keep[0] ? v[0] : 0.0f;
    oa.y = keep[1] ? v[1] : 0.0f;
    oa.z = keep[2] ? v[2] : 0.0f;
    oa.w = keep[3] ? v[3] : 0.0f;
    ob.x = keep[4] ? v[4] : 0.0f;
    ob.y = keep[5] ? v[5] : 0.0f;
    ob.z = keep[6] ? v[6] : 0.0f;
    ob.w = keep[7] ? v[7] : 0.0f;
    float4* o4 = reinterpret_cast<float4*>(out + base);
    o4[lane] = oa;
    o4[lane + 64u] = ob;
}

extern "C" void kernel_launch(void* const* d_in, const int* in_sizes, int n_in,
                              void* d_out, int out_size, void* d_ws, size_t ws_size,
                              hipStream_t stream) {
    const float* x = (const float*)d_in[0];
    float* out = (float*)d_out;
    const int total = in_sizes[0];          // 16384 * 4096
    const int waves = total / 512;          // one wave per 512-elem block
    const int blocks = waves / 4;           // 256 threads = 4 waves per WG
    wta_kernel<<<blocks, 256, 0, stream>>>(x, out);
}